// Round 10
// baseline (253.644 us; speedup 1.0000x reference)
//
#include <hip/hip_runtime.h>
#include <cmath>
#include <type_traits>

#define HEADS 4
#define FDIM 128   // H*D == IN_DIM == 128
#define NEG 0.2f
#define NBUCK 8    // src-locality buckets per dst segment

typedef __attribute__((ext_vector_type(8))) __bf16 bf16x8;
typedef __attribute__((ext_vector_type(8))) _Float16 h16x8;
typedef __attribute__((ext_vector_type(4))) float f32x4;

// ---------------------------------------------------------------------------
// Unified W preprocessing + counts zeroing, one dispatch:
//   blocks 0..127   : wfrag W1      blocks 128..255 : wfrag W2
//   block 256/257   : valcomp+wext W1/W2
//   blocks 258..    : zero counts[NB]
// ---------------------------------------------------------------------------
__global__ __launch_bounds__(256) void prep_kernel(
    const float* __restrict__ W1, const float* __restrict__ al1,
    const float* __restrict__ ar1,
    const float* __restrict__ W2, const float* __restrict__ al2,
    const float* __restrict__ ar2,
    __bf16* __restrict__ wf1, __bf16* __restrict__ wext1,
    __bf16* __restrict__ wf2, __bf16* __restrict__ wext2,
    int* __restrict__ counts, int nb)
{
    const int b = blockIdx.x, tid = threadIdx.x;
    if (b < 256) {
        const float* W = (b < 128) ? W1 : W2;
        __bf16* wf = (b < 128) ? wf1 : wf2;
        int idx = (b & 127) * 256 + tid;        // < 32768
        int j = idx & 7;
        int r = idx >> 3;
        int c = r & 15; r >>= 4;
        int t = r & 7;  r >>= 3;
        int kq = r & 15;
        int hl = r >> 4;
        float v = W[(t * 16 + c) * 128 + kq * 8 + j];
        __bf16 hi = (__bf16)v;
        wf[idx] = (hl == 0) ? hi : (__bf16)(v - (float)hi);
    } else if (b < 258) {
        const float* W  = (b == 256) ? W1 : W2;
        const float* al = (b == 256) ? al1 : al2;
        const float* ar = (b == 256) ? ar1 : ar2;
        __bf16* wext = (b == 256) ? wext1 : wext2;
        __shared__ float val[1024];
        #pragma unroll
        for (int ch = 0; ch < 4; ++ch) {
            int idx = ch * 256 + tid;           // < 1024
            int c = idx >> 7, k = idx & 127;
            int h = c & 3;
            const float* a = (c < 4) ? al : ar;
            float s = 0.f;
            for (int d = 0; d < 32; ++d)
                s += a[h * 32 + d] * W[(h * 32 + d) * 128 + k];
            val[c * 128 + k] = s;
        }
        __syncthreads();
        #pragma unroll
        for (int ch = 0; ch < 16; ++ch) {
            int idx = tid * 16 + ch;            // < 4096
            int j = idx & 7;
            int r = idx >> 3;
            int c = r & 15; r >>= 4;
            int kq = r & 15;
            int hl = r >> 4;
            float v = (c < 8) ? val[c * 128 + kq * 8 + j] : 0.f;
            __bf16 hi = (__bf16)v;
            wext[idx] = (hl == 0) ? hi : (__bf16)(v - (float)hi);
        }
    } else {
        int i0 = ((b - 258) * 256 + tid) * 4;
        if (i0 + 3 < nb) {
            *(int4*)&counts[i0] = make_int4(0, 0, 0, 0);
        } else {
            for (int i = i0; i < nb; ++i) counts[i] = 0;
        }
    }
}

// ---------------------------------------------------------------------------
// MFMA GEMM, LDS-staged W (64 KB), grid-stride tiles, X reg-prefetch.
// Templated on input dtype (f32 or fp16; fp16 -> split-bf16 is exact).
// acc[0..7] = feat cols (stored fp16), acc[8] = el (cols 0-3) / er (cols 4-7).
// ---------------------------------------------------------------------------
template <typename XT>
__global__ __launch_bounds__(256) void gemm_mfma_kernel(
    const XT* __restrict__ X, const bf16x8* __restrict__ wf,
    const bf16x8* __restrict__ wext,
    _Float16* __restrict__ featH,
    float* __restrict__ el, float* __restrict__ er,
    int nnodes, int ntiles)
{
    __shared__ bf16x8 lw[4096];   // 65536 B
    const int tid = threadIdx.x;
    for (int i = tid; i < 4096; i += 256) lw[i] = wf[i];
    __syncthreads();

    const int wave = tid >> 6, lane = tid & 63;
    const int l15 = lane & 15, quad = lane >> 4;

    int tile = blockIdx.x;
    float xr[32], xn[32];

    auto loadX = [&](int tl, float* dst) {
        int nodeA = tl * 64 + wave * 16 + l15;
        bool v = nodeA < nnodes;
        if constexpr (std::is_same<XT, float>::value) {
            const float4* xp = (const float4*)(X + (size_t)nodeA * 128);
            #pragma unroll
            for (int ks = 0; ks < 4; ++ks) {
                float4 a = v ? xp[ks * 8 + quad * 2]     : make_float4(0.f, 0.f, 0.f, 0.f);
                float4 b = v ? xp[ks * 8 + quad * 2 + 1] : make_float4(0.f, 0.f, 0.f, 0.f);
                dst[ks * 8 + 0] = a.x; dst[ks * 8 + 1] = a.y;
                dst[ks * 8 + 2] = a.z; dst[ks * 8 + 3] = a.w;
                dst[ks * 8 + 4] = b.x; dst[ks * 8 + 5] = b.y;
                dst[ks * 8 + 6] = b.z; dst[ks * 8 + 7] = b.w;
            }
        } else {
            const h16x8* xp = (const h16x8*)(X + (size_t)nodeA * 128);
            #pragma unroll
            for (int ks = 0; ks < 4; ++ks) {
                h16x8 hv;
                if (v) {
                    hv = xp[ks * 4 + quad];
                } else {
                    #pragma unroll
                    for (int j = 0; j < 8; ++j) hv[j] = (_Float16)0.f;
                }
                #pragma unroll
                for (int j = 0; j < 8; ++j) dst[ks * 8 + j] = (float)hv[j];
            }
        }
    };

    loadX(tile, xr);
    while (true) {
        int next = tile + gridDim.x;
        if (next < ntiles) loadX(next, xn);

        f32x4 acc[9];
        #pragma unroll
        for (int t = 0; t < 9; ++t) acc[t] = (f32x4){0.f, 0.f, 0.f, 0.f};

        #pragma unroll
        for (int ks = 0; ks < 4; ++ks) {
            bf16x8 ahi, alo;
            #pragma unroll
            for (int j = 0; j < 8; ++j) {
                float xv = xr[ks * 8 + j];
                __bf16 h = (__bf16)xv;
                ahi[j] = h;
                alo[j] = (__bf16)(xv - (float)h);
            }
            const int kq = ks * 4 + quad;

            {
                bf16x8 bh = wext[(kq) * 16 + l15];
                bf16x8 bl = wext[(16 + kq) * 16 + l15];
                acc[8] = __builtin_amdgcn_mfma_f32_16x16x32_bf16(ahi, bh, acc[8], 0, 0, 0);
                acc[8] = __builtin_amdgcn_mfma_f32_16x16x32_bf16(alo, bh, acc[8], 0, 0, 0);
                acc[8] = __builtin_amdgcn_mfma_f32_16x16x32_bf16(ahi, bl, acc[8], 0, 0, 0);
            }
            #pragma unroll
            for (int t = 0; t < 8; ++t) {
                bf16x8 bh = lw[(kq * 8 + t) * 16 + l15];
                bf16x8 bl = lw[((16 + kq) * 8 + t) * 16 + l15];
                acc[t] = __builtin_amdgcn_mfma_f32_16x16x32_bf16(ahi, bh, acc[t], 0, 0, 0);
                acc[t] = __builtin_amdgcn_mfma_f32_16x16x32_bf16(alo, bh, acc[t], 0, 0, 0);
                acc[t] = __builtin_amdgcn_mfma_f32_16x16x32_bf16(ahi, bl, acc[t], 0, 0, 0);
            }
        }

        const int nodeC = tile * 64 + wave * 16 + quad * 4;
        #pragma unroll
        for (int r = 0; r < 4; ++r) {
            int gn = nodeC + r;
            if (gn < nnodes) {
                #pragma unroll
                for (int t = 0; t < 8; ++t)
                    featH[(size_t)gn * 128 + t * 16 + l15] = (_Float16)acc[t][r];
            }
        }
        if (l15 < 8) {
            #pragma unroll
            for (int r = 0; r < 4; ++r) {
                int gn = nodeC + r;
                if (gn < nnodes) {
                    if (l15 < 4) el[gn * HEADS + l15] = acc[8][r];
                    else         er[gn * HEADS + (l15 - 4)] = acc[8][r];
                }
            }
        }

        if (next >= ntiles) break;
        #pragma unroll
        for (int i = 0; i < 32; ++i) xr[i] = xn[i];
        tile = next;
    }
}

// ---------------------------------------------------------------------------
// Bucketed CSR build: bin = dst*8 + (src>>shift). hist captures within-bin
// rank from the atomic return; scatter is atomic-free.
// ---------------------------------------------------------------------------
__global__ __launch_bounds__(256) void hist_kernel(
    const int* __restrict__ src, const int* __restrict__ dst,
    int* __restrict__ counts, int* __restrict__ rank, int nedges, int shift)
{
    int i0 = (blockIdx.x * 256 + threadIdx.x) * 4;
    if (i0 + 3 < nedges) {
        int4 d = *(const int4*)&dst[i0];
        int4 s = *(const int4*)&src[i0];
        int4 r;
        r.x = atomicAdd(&counts[d.x * NBUCK + (s.x >> shift)], 1);
        r.y = atomicAdd(&counts[d.y * NBUCK + (s.y >> shift)], 1);
        r.z = atomicAdd(&counts[d.z * NBUCK + (s.z >> shift)], 1);
        r.w = atomicAdd(&counts[d.w * NBUCK + (s.w >> shift)], 1);
        *(int4*)&rank[i0] = r;
    } else {
        for (int i = i0; i < nedges; ++i)
            rank[i] = atomicAdd(&counts[dst[i] * NBUCK + (src[i] >> shift)], 1);
    }
}

__global__ __launch_bounds__(256) void scan1_kernel(
    const int* __restrict__ counts, int* __restrict__ offsets,
    int* __restrict__ bsums, int n)
{
    __shared__ int wsums[4];
    const int tid = threadIdx.x, lane = tid & 63, w = tid >> 6;
    const int i = blockIdx.x * 1024 + tid * 4;

    int4 v = make_int4(0, 0, 0, 0);
    if (i + 3 < n) v = *(const int4*)&counts[i];
    else {
        if (i < n)     v.x = counts[i];
        if (i + 1 < n) v.y = counts[i + 1];
        if (i + 2 < n) v.z = counts[i + 2];
    }
    int s0 = v.x, s1 = s0 + v.y, s2 = s1 + v.z, s3 = s2 + v.w;

    int x = s3;
    #pragma unroll
    for (int off = 1; off < 64; off <<= 1) {
        int t = __shfl_up(x, off, 64);
        if (lane >= off) x += t;
    }
    if (lane == 63) wsums[w] = x;
    __syncthreads();
    int wbase = 0;
    #pragma unroll
    for (int k = 0; k < 4; ++k) if (k < w) wbase += wsums[k];

    int tbase = wbase + x - s3;
    if (i < n)     offsets[i]     = tbase;
    if (i + 1 < n) offsets[i + 1] = tbase + s0;
    if (i + 2 < n) offsets[i + 2] = tbase + s1;
    if (i + 3 < n) offsets[i + 3] = tbase + s2;
    if (tid == 255) bsums[blockIdx.x] = wbase + x;
}

// scan2 folded in: each block wave-reduces bsums[0..b) itself, then adds.
__global__ __launch_bounds__(256) void scan23_kernel(
    int* __restrict__ offsets, const int* __restrict__ bsums, int n, int nedges)
{
    __shared__ int sbase;
    const int tid = threadIdx.x, b = blockIdx.x;
    if (tid < 64) {
        int s = 0;
        for (int i = tid; i < b; i += 64) s += bsums[i];
        #pragma unroll
        for (int off = 1; off < 64; off <<= 1) s += __shfl_xor(s, off, 64);
        if (tid == 0) sbase = s;
    }
    __syncthreads();
    const int base = sbase;
    const int i = b * 1024 + tid * 4;
    #pragma unroll
    for (int k = 0; k < 4; ++k)
        if (i + k < n) offsets[i + k] += base;
    if (b == 0 && tid == 0) offsets[n] = nedges;
}

__global__ __launch_bounds__(256) void scatter_kernel(
    const int* __restrict__ src, const int* __restrict__ dst,
    const int* __restrict__ rank, const int* __restrict__ offsets,
    int* __restrict__ csr_src, int nedges, int shift)
{
    int i0 = (blockIdx.x * 256 + threadIdx.x) * 4;
    if (i0 + 3 < nedges) {
        int4 d = *(const int4*)&dst[i0];
        int4 r = *(const int4*)&rank[i0];
        int4 s = *(const int4*)&src[i0];
        csr_src[offsets[d.x * NBUCK + (s.x >> shift)] + r.x] = s.x;
        csr_src[offsets[d.y * NBUCK + (s.y >> shift)] + r.y] = s.y;
        csr_src[offsets[d.z * NBUCK + (s.z >> shift)] + r.z] = s.z;
        csr_src[offsets[d.w * NBUCK + (s.w >> shift)] + r.w] = s.w;
    } else {
        for (int i = i0; i < nedges; ++i)
            csr_src[offsets[dst[i] * NBUCK + (src[i] >> shift)] + rank[i]] = src[i];
    }
}

// ---------------------------------------------------------------------------
// Gather aggregation: ONE WAVE PER NODE, 4 edges/iteration (16 lanes/edge,
// 8 fp16 feats/lane). iters = ceil(deg/4) exactly — no max-degree waste.
// Cross-group (edge-slot) reduction in the epilogue via shfl_xor 16/32.
// ---------------------------------------------------------------------------
template <bool MEAN>
__global__ __launch_bounds__(256) void aggregate_kernel(
    const _Float16* __restrict__ featH, const float* __restrict__ el,
    const float* __restrict__ er, const int* __restrict__ offsets,
    const int* __restrict__ csr_src, void* __restrict__ outp, int nnodes)
{
    const int n = (blockIdx.x * 256 + threadIdx.x) >> 6;   // wave-uniform
    if (n >= nnodes) return;
    const int lane = threadIdx.x & 63;
    const int g = lane >> 4, u = lane & 15, h = u >> 2;
    const int beg = offsets[n * NBUCK], end = offsets[n * NBUCK + NBUCK];
    const float ern = er[n * HEADS + h];
    const int iters = (end - beg + 3) >> 2;

    float a[8];
    #pragma unroll
    for (int p = 0; p < 8; ++p) a[p] = 0.f;
    float sw = 0.f;

    int j = beg + g;
    bool v = j < end;
    int s = v ? csr_src[j] : 0;
    float q = el[s * HEADS + h];
    h16x8 f = ((const h16x8*)(featH + (size_t)s * 128))[u];

    for (int it = 0; it < iters; ++it) {
        int jn = j + 4;
        bool vn = jn < end;
        int sn = vn ? csr_src[jn] : 0;
        float qn = el[sn * HEADS + h];
        h16x8 fn = ((const h16x8*)(featH + (size_t)sn * 128))[u];

        float e = q + ern;
        e = e > 0.f ? e : NEG * e;
        float w = v ? __expf(e) : 0.f;
        #pragma unroll
        for (int p = 0; p < 8; ++p) a[p] += w * (float)f[p];
        sw += w;

        j = jn; v = vn; q = qn; f = fn;
    }

    // reduce the 4 edge-slot groups (lanes u, u+16, u+32, u+48)
    #pragma unroll
    for (int p = 0; p < 8; ++p) {
        a[p] += __shfl_xor(a[p], 16, 64);
        a[p] += __shfl_xor(a[p], 32, 64);
    }
    sw += __shfl_xor(sw, 16, 64);
    sw += __shfl_xor(sw, 32, 64);

    float inv = sw > 0.f ? 1.f / sw : 0.f;
    float r[8];
    #pragma unroll
    for (int p = 0; p < 8; ++p) {
        float t = a[p] * inv;
        r[p] = t > 0.f ? t : expm1f(t);
    }

    if (!MEAN) {
        if (g == 0) {
            h16x8 o;
            #pragma unroll
            for (int p = 0; p < 8; ++p) o[p] = (_Float16)r[p];
            ((h16x8*)outp)[(size_t)n * 16 + u] = o;
        }
    } else {
        #pragma unroll
        for (int p = 0; p < 8; ++p) {
            r[p] += __shfl_xor(r[p], 4, 64);
            r[p] += __shfl_xor(r[p], 8, 64);
        }
        if (g == 0 && u < 4) {
            float* out = (float*)outp;
            float4* o4 = (float4*)(out + (size_t)n * 32 + u * 8);
            o4[0] = make_float4(0.25f * r[0], 0.25f * r[1], 0.25f * r[2], 0.25f * r[3]);
            o4[1] = make_float4(0.25f * r[4], 0.25f * r[5], 0.25f * r[6], 0.25f * r[7]);
        }
    }
}

// ---------------------------------------------------------------------------
extern "C" void kernel_launch(void* const* d_in, const int* in_sizes, int n_in,
                              void* d_out, int out_size, void* d_ws, size_t ws_size,
                              hipStream_t stream)
{
    const float* x   = (const float*)d_in[0];
    const int*   src = (const int*)d_in[1];
    const int*   dst = (const int*)d_in[2];
    const float* W1  = (const float*)d_in[3];
    const float* al1 = (const float*)d_in[4];
    const float* ar1 = (const float*)d_in[5];
    const float* W2  = (const float*)d_in[6];
    const float* al2 = (const float*)d_in[7];
    const float* ar2 = (const float*)d_in[8];

    const int N = in_sizes[0] / FDIM;
    const int E = in_sizes[1];
    const int NB = N * NBUCK;

    int shift = 0;
    while (((N - 1) >> shift) > (NBUCK - 1)) ++shift;

    // workspace: h1[N*128] fp16 | featH[N*128] fp16 | el[N*4] | er[N*4] |
    //   counts[8N] | offsets[8N+1] | rank[E] | csr_src[E] | bsums[512] | W imgs
    _Float16* h1 = (_Float16*)d_ws;
    _Float16* featH = h1 + (size_t)N * FDIM;
    float* el = (float*)(featH + (size_t)N * FDIM);
    float* er = el + (size_t)N * HEADS;
    int* counts  = (int*)(er + (size_t)N * HEADS);
    int* offsets = counts + NB;
    int* rank    = offsets + (NB + 1);
    int* csr_src = rank + E;
    int* bsums   = csr_src + E;
    uintptr_t wp = ((uintptr_t)(bsums + 512) + 63) & ~(uintptr_t)63;
    __bf16* wf1   = (__bf16*)wp;             // 32768 bf16
    __bf16* wext1 = wf1 + 32768;             // 4096 bf16
    __bf16* wf2   = wext1 + 4096;
    __bf16* wext2 = wf2 + 32768;

    const int ntiles = (N + 63) / 64;
    const int gemm_grid = ntiles < 256 ? ntiles : 256;
    const int edge4_grid = ((E + 3) / 4 + 255) / 256;
    const int agg_grid  = (N + 3) / 4;             // 1 wave/node, 4 waves/block
    const int nscan     = (NB + 1023) / 1024;
    const int zblocks   = ((NB + 3) / 4 + 255) / 256;

    // ---- W preprocessing + counts zeroing (one dispatch) ----
    prep_kernel<<<258 + zblocks, 256, 0, stream>>>(
        W1, al1, ar1, W2, al2, ar2, wf1, wext1, wf2, wext2, counts, NB);

    // ---- bucketed CSR build (once; shared by both layers) ----
    hist_kernel<<<edge4_grid, 256, 0, stream>>>(src, dst, counts, rank, E, shift);
    scan1_kernel<<<nscan, 256, 0, stream>>>(counts, offsets, bsums, NB);
    scan23_kernel<<<nscan, 256, 0, stream>>>(offsets, bsums, NB, E);
    scatter_kernel<<<edge4_grid, 256, 0, stream>>>(src, dst, rank, offsets,
                                                   csr_src, E, shift);

    // ---- layer 1 ----
    gemm_mfma_kernel<float><<<gemm_grid, 256, 0, stream>>>(
        x, (const bf16x8*)wf1, (const bf16x8*)wext1, featH, el, er, N, ntiles);
    aggregate_kernel<false><<<agg_grid, 256, 0, stream>>>(
        featH, el, er, offsets, csr_src, (void*)h1, N);

    // ---- layer 2 ----
    gemm_mfma_kernel<_Float16><<<gemm_grid, 256, 0, stream>>>(
        h1, (const bf16x8*)wf2, (const bf16x8*)wext2, featH, el, er, N, ntiles);
    aggregate_kernel<true><<<agg_grid, 256, 0, stream>>>(
        featH, el, er, offsets, csr_src, d_out, N);
}

// Round 11
// 251.772 us; speedup vs baseline: 1.0074x; 1.0074x over previous
//
#include <hip/hip_runtime.h>
#include <cmath>
#include <type_traits>

#define HEADS 4
#define FDIM 128   // H*D == IN_DIM == 128
#define NEG 0.2f
#define NBUCK 8    // src-locality buckets per dst segment

typedef __attribute__((ext_vector_type(8))) __bf16 bf16x8;
typedef __attribute__((ext_vector_type(8))) _Float16 h16x8;
typedef __attribute__((ext_vector_type(4))) float f32x4;

// ---------------------------------------------------------------------------
// Unified W preprocessing + counts zeroing, one dispatch:
//   blocks 0..127   : wfrag W1      blocks 128..255 : wfrag W2
//   block 256/257   : valcomp+wext W1/W2
//   blocks 258..    : zero counts[NB]
// ---------------------------------------------------------------------------
__global__ __launch_bounds__(256) void prep_kernel(
    const float* __restrict__ W1, const float* __restrict__ al1,
    const float* __restrict__ ar1,
    const float* __restrict__ W2, const float* __restrict__ al2,
    const float* __restrict__ ar2,
    __bf16* __restrict__ wf1, __bf16* __restrict__ wext1,
    __bf16* __restrict__ wf2, __bf16* __restrict__ wext2,
    int* __restrict__ counts, int nb)
{
    const int b = blockIdx.x, tid = threadIdx.x;
    if (b < 256) {
        const float* W = (b < 128) ? W1 : W2;
        __bf16* wf = (b < 128) ? wf1 : wf2;
        int idx = (b & 127) * 256 + tid;        // < 32768
        int j = idx & 7;
        int r = idx >> 3;
        int c = r & 15; r >>= 4;
        int t = r & 7;  r >>= 3;
        int kq = r & 15;
        int hl = r >> 4;
        float v = W[(t * 16 + c) * 128 + kq * 8 + j];
        __bf16 hi = (__bf16)v;
        wf[idx] = (hl == 0) ? hi : (__bf16)(v - (float)hi);
    } else if (b < 258) {
        const float* W  = (b == 256) ? W1 : W2;
        const float* al = (b == 256) ? al1 : al2;
        const float* ar = (b == 256) ? ar1 : ar2;
        __bf16* wext = (b == 256) ? wext1 : wext2;
        __shared__ float val[1024];
        #pragma unroll
        for (int ch = 0; ch < 4; ++ch) {
            int idx = ch * 256 + tid;           // < 1024
            int c = idx >> 7, k = idx & 127;
            int h = c & 3;
            const float* a = (c < 4) ? al : ar;
            float s = 0.f;
            for (int d = 0; d < 32; ++d)
                s += a[h * 32 + d] * W[(h * 32 + d) * 128 + k];
            val[c * 128 + k] = s;
        }
        __syncthreads();
        #pragma unroll
        for (int ch = 0; ch < 16; ++ch) {
            int idx = tid * 16 + ch;            // < 4096
            int j = idx & 7;
            int r = idx >> 3;
            int c = r & 15; r >>= 4;
            int kq = r & 15;
            int hl = r >> 4;
            float v = (c < 8) ? val[c * 128 + kq * 8 + j] : 0.f;
            __bf16 hi = (__bf16)v;
            wext[idx] = (hl == 0) ? hi : (__bf16)(v - (float)hi);
        }
    } else {
        int i0 = ((b - 258) * 256 + tid) * 4;
        if (i0 + 3 < nb) {
            *(int4*)&counts[i0] = make_int4(0, 0, 0, 0);
        } else {
            for (int i = i0; i < nb; ++i) counts[i] = 0;
        }
    }
}

// ---------------------------------------------------------------------------
// MFMA GEMM. W-hi staged in LDS (32 KB -> 2 blocks/CU); W-lo read from
// global (L1/L2-resident, coalesced). Grid-stride tiles, X reg-prefetch
// issued BEFORE the LDS staging loop.
// acc[0..7] = feat cols (stored fp16), acc[8] = el (cols 0-3) / er (cols 4-7).
// ---------------------------------------------------------------------------
template <typename XT>
__global__ __launch_bounds__(256) void gemm_mfma_kernel(
    const XT* __restrict__ X, const bf16x8* __restrict__ wf,
    const bf16x8* __restrict__ wext,
    _Float16* __restrict__ featH,
    float* __restrict__ el, float* __restrict__ er,
    int nnodes, int ntiles)
{
    __shared__ bf16x8 lw[2048];   // 32768 B: hi half only
    const int tid = threadIdx.x;
    const int wave = tid >> 6, lane = tid & 63;
    const int l15 = lane & 15, quad = lane >> 4;

    int tile = blockIdx.x;
    float xr[32], xn[32];

    auto loadX = [&](int tl, float* dst) {
        int nodeA = tl * 64 + wave * 16 + l15;
        bool v = nodeA < nnodes;
        if constexpr (std::is_same<XT, float>::value) {
            const float4* xp = (const float4*)(X + (size_t)nodeA * 128);
            #pragma unroll
            for (int ks = 0; ks < 4; ++ks) {
                float4 a = v ? xp[ks * 8 + quad * 2]     : make_float4(0.f, 0.f, 0.f, 0.f);
                float4 b = v ? xp[ks * 8 + quad * 2 + 1] : make_float4(0.f, 0.f, 0.f, 0.f);
                dst[ks * 8 + 0] = a.x; dst[ks * 8 + 1] = a.y;
                dst[ks * 8 + 2] = a.z; dst[ks * 8 + 3] = a.w;
                dst[ks * 8 + 4] = b.x; dst[ks * 8 + 5] = b.y;
                dst[ks * 8 + 6] = b.z; dst[ks * 8 + 7] = b.w;
            }
        } else {
            const h16x8* xp = (const h16x8*)(X + (size_t)nodeA * 128);
            #pragma unroll
            for (int ks = 0; ks < 4; ++ks) {
                h16x8 hv;
                if (v) {
                    hv = xp[ks * 4 + quad];
                } else {
                    #pragma unroll
                    for (int j = 0; j < 8; ++j) hv[j] = (_Float16)0.f;
                }
                #pragma unroll
                for (int j = 0; j < 8; ++j) dst[ks * 8 + j] = (float)hv[j];
            }
        }
    };

    loadX(tile, xr);                      // issue X loads first
    for (int i = tid; i < 2048; i += 256) lw[i] = wf[i];
    __syncthreads();

    while (true) {
        int next = tile + gridDim.x;
        if (next < ntiles) loadX(next, xn);

        f32x4 acc[9];
        #pragma unroll
        for (int t = 0; t < 9; ++t) acc[t] = (f32x4){0.f, 0.f, 0.f, 0.f};

        #pragma unroll
        for (int ks = 0; ks < 4; ++ks) {
            bf16x8 ahi, alo;
            #pragma unroll
            for (int j = 0; j < 8; ++j) {
                float xv = xr[ks * 8 + j];
                __bf16 h = (__bf16)xv;
                ahi[j] = h;
                alo[j] = (__bf16)(xv - (float)h);
            }
            const int kq = ks * 4 + quad;

            {
                bf16x8 bh = wext[(kq) * 16 + l15];
                bf16x8 bl = wext[(16 + kq) * 16 + l15];
                acc[8] = __builtin_amdgcn_mfma_f32_16x16x32_bf16(ahi, bh, acc[8], 0, 0, 0);
                acc[8] = __builtin_amdgcn_mfma_f32_16x16x32_bf16(alo, bh, acc[8], 0, 0, 0);
                acc[8] = __builtin_amdgcn_mfma_f32_16x16x32_bf16(ahi, bl, acc[8], 0, 0, 0);
            }
            #pragma unroll
            for (int t = 0; t < 8; ++t) {
                bf16x8 bh = lw[(kq * 8 + t) * 16 + l15];
                bf16x8 bl = wf[2048 + (kq * 8 + t) * 16 + l15];   // lo from global
                acc[t] = __builtin_amdgcn_mfma_f32_16x16x32_bf16(ahi, bh, acc[t], 0, 0, 0);
                acc[t] = __builtin_amdgcn_mfma_f32_16x16x32_bf16(alo, bh, acc[t], 0, 0, 0);
                acc[t] = __builtin_amdgcn_mfma_f32_16x16x32_bf16(ahi, bl, acc[t], 0, 0, 0);
            }
        }

        const int nodeC = tile * 64 + wave * 16 + quad * 4;
        #pragma unroll
        for (int r = 0; r < 4; ++r) {
            int gn = nodeC + r;
            if (gn < nnodes) {
                #pragma unroll
                for (int t = 0; t < 8; ++t)
                    featH[(size_t)gn * 128 + t * 16 + l15] = (_Float16)acc[t][r];
            }
        }
        if (l15 < 8) {
            #pragma unroll
            for (int r = 0; r < 4; ++r) {
                int gn = nodeC + r;
                if (gn < nnodes) {
                    if (l15 < 4) el[gn * HEADS + l15] = acc[8][r];
                    else         er[gn * HEADS + (l15 - 4)] = acc[8][r];
                }
            }
        }

        if (next >= ntiles) break;
        #pragma unroll
        for (int i = 0; i < 32; ++i) xr[i] = xn[i];
        tile = next;
    }
}

// ---------------------------------------------------------------------------
// Bucketed CSR build: bin = dst*8 + (src>>shift). hist captures within-bin
// rank from the atomic return; scatter is atomic-free. 8 edges/thread for MLP.
// ---------------------------------------------------------------------------
__global__ __launch_bounds__(256) void hist_kernel(
    const int* __restrict__ src, const int* __restrict__ dst,
    int* __restrict__ counts, int* __restrict__ rank, int nedges, int shift)
{
    int i0 = (blockIdx.x * 256 + threadIdx.x) * 8;
    if (i0 + 7 < nedges) {
        int4 d0 = *(const int4*)&dst[i0];
        int4 d1 = *(const int4*)&dst[i0 + 4];
        int4 s0 = *(const int4*)&src[i0];
        int4 s1 = *(const int4*)&src[i0 + 4];
        int4 r0, r1;
        r0.x = atomicAdd(&counts[d0.x * NBUCK + (s0.x >> shift)], 1);
        r0.y = atomicAdd(&counts[d0.y * NBUCK + (s0.y >> shift)], 1);
        r0.z = atomicAdd(&counts[d0.z * NBUCK + (s0.z >> shift)], 1);
        r0.w = atomicAdd(&counts[d0.w * NBUCK + (s0.w >> shift)], 1);
        r1.x = atomicAdd(&counts[d1.x * NBUCK + (s1.x >> shift)], 1);
        r1.y = atomicAdd(&counts[d1.y * NBUCK + (s1.y >> shift)], 1);
        r1.z = atomicAdd(&counts[d1.z * NBUCK + (s1.z >> shift)], 1);
        r1.w = atomicAdd(&counts[d1.w * NBUCK + (s1.w >> shift)], 1);
        *(int4*)&rank[i0]     = r0;
        *(int4*)&rank[i0 + 4] = r1;
    } else {
        for (int i = i0; i < nedges; ++i)
            rank[i] = atomicAdd(&counts[dst[i] * NBUCK + (src[i] >> shift)], 1);
    }
}

__global__ __launch_bounds__(256) void scan1_kernel(
    const int* __restrict__ counts, int* __restrict__ offsets,
    int* __restrict__ bsums, int n)
{
    __shared__ int wsums[4];
    const int tid = threadIdx.x, lane = tid & 63, w = tid >> 6;
    const int i = blockIdx.x * 1024 + tid * 4;

    int4 v = make_int4(0, 0, 0, 0);
    if (i + 3 < n) v = *(const int4*)&counts[i];
    else {
        if (i < n)     v.x = counts[i];
        if (i + 1 < n) v.y = counts[i + 1];
        if (i + 2 < n) v.z = counts[i + 2];
    }
    int s0 = v.x, s1 = s0 + v.y, s2 = s1 + v.z, s3 = s2 + v.w;

    int x = s3;
    #pragma unroll
    for (int off = 1; off < 64; off <<= 1) {
        int t = __shfl_up(x, off, 64);
        if (lane >= off) x += t;
    }
    if (lane == 63) wsums[w] = x;
    __syncthreads();
    int wbase = 0;
    #pragma unroll
    for (int k = 0; k < 4; ++k) if (k < w) wbase += wsums[k];

    int tbase = wbase + x - s3;
    if (i < n)     offsets[i]     = tbase;
    if (i + 1 < n) offsets[i + 1] = tbase + s0;
    if (i + 2 < n) offsets[i + 2] = tbase + s1;
    if (i + 3 < n) offsets[i + 3] = tbase + s2;
    if (tid == 255) bsums[blockIdx.x] = wbase + x;
}

// scan2 folded in: each block wave-reduces bsums[0..b) itself, then adds.
__global__ __launch_bounds__(256) void scan23_kernel(
    int* __restrict__ offsets, const int* __restrict__ bsums, int n, int nedges)
{
    __shared__ int sbase;
    const int tid = threadIdx.x, b = blockIdx.x;
    if (tid < 64) {
        int s = 0;
        for (int i = tid; i < b; i += 64) s += bsums[i];
        #pragma unroll
        for (int off = 1; off < 64; off <<= 1) s += __shfl_xor(s, off, 64);
        if (tid == 0) sbase = s;
    }
    __syncthreads();
    const int base = sbase;
    const int i = b * 1024 + tid * 4;
    #pragma unroll
    for (int k = 0; k < 4; ++k)
        if (i + k < n) offsets[i + k] += base;
    if (b == 0 && tid == 0) offsets[n] = nedges;
}

__global__ __launch_bounds__(256) void scatter_kernel(
    const int* __restrict__ src, const int* __restrict__ dst,
    const int* __restrict__ rank, const int* __restrict__ offsets,
    int* __restrict__ csr_src, int nedges, int shift)
{
    int i0 = (blockIdx.x * 256 + threadIdx.x) * 8;
    if (i0 + 7 < nedges) {
        int4 d0 = *(const int4*)&dst[i0];
        int4 d1 = *(const int4*)&dst[i0 + 4];
        int4 r0 = *(const int4*)&rank[i0];
        int4 r1 = *(const int4*)&rank[i0 + 4];
        int4 s0 = *(const int4*)&src[i0];
        int4 s1 = *(const int4*)&src[i0 + 4];
        csr_src[offsets[d0.x * NBUCK + (s0.x >> shift)] + r0.x] = s0.x;
        csr_src[offsets[d0.y * NBUCK + (s0.y >> shift)] + r0.y] = s0.y;
        csr_src[offsets[d0.z * NBUCK + (s0.z >> shift)] + r0.z] = s0.z;
        csr_src[offsets[d0.w * NBUCK + (s0.w >> shift)] + r0.w] = s0.w;
        csr_src[offsets[d1.x * NBUCK + (s1.x >> shift)] + r1.x] = s1.x;
        csr_src[offsets[d1.y * NBUCK + (s1.y >> shift)] + r1.y] = s1.y;
        csr_src[offsets[d1.z * NBUCK + (s1.z >> shift)] + r1.z] = s1.z;
        csr_src[offsets[d1.w * NBUCK + (s1.w >> shift)] + r1.w] = s1.w;
    } else {
        for (int i = i0; i < nedges; ++i)
            csr_src[offsets[dst[i] * NBUCK + (src[i] >> shift)] + rank[i]] = src[i];
    }
}

// ---------------------------------------------------------------------------
// Gather aggregation: one wave per node, 4 edges/iter (16 lanes/edge,
// 8 fp16 feats/lane), DEPTH-2 software pipeline (2 gathers in flight per
// edge-slot group -> more outstanding misses).
// ---------------------------------------------------------------------------
template <bool MEAN>
__global__ __launch_bounds__(256) void aggregate_kernel(
    const _Float16* __restrict__ featH, const float* __restrict__ el,
    const float* __restrict__ er, const int* __restrict__ offsets,
    const int* __restrict__ csr_src, void* __restrict__ outp, int nnodes)
{
    const int n = (blockIdx.x * 256 + threadIdx.x) >> 6;   // wave-uniform
    if (n >= nnodes) return;
    const int lane = threadIdx.x & 63;
    const int g = lane >> 4, u = lane & 15, h = u >> 2;
    const int beg = offsets[n * NBUCK], end = offsets[n * NBUCK + NBUCK];
    const float ern = er[n * HEADS + h];
    const int iters = (end - beg + 3) >> 2;

    float a[8];
    #pragma unroll
    for (int p = 0; p < 8; ++p) a[p] = 0.f;
    float sw = 0.f;

    const h16x8* __restrict__ frow = (const h16x8*)featH;

    int ja = beg + g;
    int jb = ja + 4;
    bool va = ja < end, vb = jb < end;
    int sa = va ? csr_src[ja] : 0;
    int sb = vb ? csr_src[jb] : 0;
    float qa = el[sa * HEADS + h];
    float qb = el[sb * HEADS + h];
    h16x8 fa = frow[(size_t)sa * 16 + u];
    h16x8 fb = frow[(size_t)sb * 16 + u];

    for (int it = 0; it < iters; ++it) {
        int jc = ja + 8;
        bool vc = jc < end;
        int sc = vc ? csr_src[jc] : 0;
        float qc = el[sc * HEADS + h];
        h16x8 fc = frow[(size_t)sc * 16 + u];

        float e = qa + ern;
        e = e > 0.f ? e : NEG * e;
        float w = va ? __expf(e) : 0.f;
        #pragma unroll
        for (int p = 0; p < 8; ++p) a[p] += w * (float)fa[p];
        sw += w;

        ja = jb; va = vb; sa = sb; qa = qb; fa = fb;
        jb = jc; vb = vc; sb = sc; qb = qc; fb = fc;
    }

    // reduce the 4 edge-slot groups (lanes u, u+16, u+32, u+48)
    #pragma unroll
    for (int p = 0; p < 8; ++p) {
        a[p] += __shfl_xor(a[p], 16, 64);
        a[p] += __shfl_xor(a[p], 32, 64);
    }
    sw += __shfl_xor(sw, 16, 64);
    sw += __shfl_xor(sw, 32, 64);

    float inv = sw > 0.f ? 1.f / sw : 0.f;
    float r[8];
    #pragma unroll
    for (int p = 0; p < 8; ++p) {
        float t = a[p] * inv;
        r[p] = t > 0.f ? t : expm1f(t);
    }

    if (!MEAN) {
        if (g == 0) {
            h16x8 o;
            #pragma unroll
            for (int p = 0; p < 8; ++p) o[p] = (_Float16)r[p];
            ((h16x8*)outp)[(size_t)n * 16 + u] = o;
        }
    } else {
        #pragma unroll
        for (int p = 0; p < 8; ++p) {
            r[p] += __shfl_xor(r[p], 4, 64);
            r[p] += __shfl_xor(r[p], 8, 64);
        }
        if (g == 0 && u < 4) {
            float* out = (float*)outp;
            float4* o4 = (float4*)(out + (size_t)n * 32 + u * 8);
            o4[0] = make_float4(0.25f * r[0], 0.25f * r[1], 0.25f * r[2], 0.25f * r[3]);
            o4[1] = make_float4(0.25f * r[4], 0.25f * r[5], 0.25f * r[6], 0.25f * r[7]);
        }
    }
}

// ---------------------------------------------------------------------------
extern "C" void kernel_launch(void* const* d_in, const int* in_sizes, int n_in,
                              void* d_out, int out_size, void* d_ws, size_t ws_size,
                              hipStream_t stream)
{
    const float* x   = (const float*)d_in[0];
    const int*   src = (const int*)d_in[1];
    const int*   dst = (const int*)d_in[2];
    const float* W1  = (const float*)d_in[3];
    const float* al1 = (const float*)d_in[4];
    const float* ar1 = (const float*)d_in[5];
    const float* W2  = (const float*)d_in[6];
    const float* al2 = (const float*)d_in[7];
    const float* ar2 = (const float*)d_in[8];

    const int N = in_sizes[0] / FDIM;
    const int E = in_sizes[1];
    const int NB = N * NBUCK;

    int shift = 0;
    while (((N - 1) >> shift) > (NBUCK - 1)) ++shift;

    // workspace: h1[N*128] fp16 | featH[N*128] fp16 | el[N*4] | er[N*4] |
    //   counts[8N] | offsets[8N+1] | rank[E] | csr_src[E] | bsums[512] | W imgs
    _Float16* h1 = (_Float16*)d_ws;
    _Float16* featH = h1 + (size_t)N * FDIM;
    float* el = (float*)(featH + (size_t)N * FDIM);
    float* er = el + (size_t)N * HEADS;
    int* counts  = (int*)(er + (size_t)N * HEADS);
    int* offsets = counts + NB;
    int* rank    = offsets + (NB + 1);
    int* csr_src = rank + E;
    int* bsums   = csr_src + E;
    uintptr_t wp = ((uintptr_t)(bsums + 512) + 63) & ~(uintptr_t)63;
    __bf16* wf1   = (__bf16*)wp;             // 32768 bf16
    __bf16* wext1 = wf1 + 32768;             // 4096 bf16
    __bf16* wf2   = wext1 + 4096;
    __bf16* wext2 = wf2 + 32768;

    const int ntiles = (N + 63) / 64;
    const int gemm_grid = ntiles < 512 ? ntiles : 512;
    const int edge8_grid = ((E + 7) / 8 + 255) / 256;
    const int agg_grid  = (N + 3) / 4;             // 1 wave/node, 4 waves/block
    const int nscan     = (NB + 1023) / 1024;
    const int zblocks   = ((NB + 3) / 4 + 255) / 256;

    // ---- W preprocessing + counts zeroing (one dispatch) ----
    prep_kernel<<<258 + zblocks, 256, 0, stream>>>(
        W1, al1, ar1, W2, al2, ar2, wf1, wext1, wf2, wext2, counts, NB);

    // ---- bucketed CSR build (once; shared by both layers) ----
    hist_kernel<<<edge8_grid, 256, 0, stream>>>(src, dst, counts, rank, E, shift);
    scan1_kernel<<<nscan, 256, 0, stream>>>(counts, offsets, bsums, NB);
    scan23_kernel<<<nscan, 256, 0, stream>>>(offsets, bsums, NB, E);
    scatter_kernel<<<edge8_grid, 256, 0, stream>>>(src, dst, rank, offsets,
                                                   csr_src, E, shift);

    // ---- layer 1 ----
    gemm_mfma_kernel<float><<<gemm_grid, 256, 0, stream>>>(
        x, (const bf16x8*)wf1, (const bf16x8*)wext1, featH, el, er, N, ntiles);
    aggregate_kernel<false><<<agg_grid, 256, 0, stream>>>(
        featH, el, er, offsets, csr_src, (void*)h1, N);

    // ---- layer 2 ----
    gemm_mfma_kernel<_Float16><<<gemm_grid, 256, 0, stream>>>(
        h1, (const bf16x8*)wf2, (const bf16x8*)wext2, featH, el, er, N, ntiles);
    aggregate_kernel<true><<<agg_grid, 256, 0, stream>>>(
        featH, el, er, offsets, csr_src, d_out, N);
}

// Round 12
// 249.961 us; speedup vs baseline: 1.0147x; 1.0072x over previous
//
#include <hip/hip_runtime.h>
#include <cmath>
#include <type_traits>

#define HEADS 4
#define FDIM 128   // H*D == IN_DIM == 128
#define NEG 0.2f
#define NBUCK 8    // src-locality buckets per dst segment

typedef __attribute__((ext_vector_type(8))) __bf16 bf16x8;
typedef __attribute__((ext_vector_type(8))) _Float16 h16x8;
typedef __attribute__((ext_vector_type(4))) float f32x4;

// ---------------------------------------------------------------------------
// Unified W preprocessing + counts zeroing, one dispatch.
// ---------------------------------------------------------------------------
__global__ __launch_bounds__(256) void prep_kernel(
    const float* __restrict__ W1, const float* __restrict__ al1,
    const float* __restrict__ ar1,
    const float* __restrict__ W2, const float* __restrict__ al2,
    const float* __restrict__ ar2,
    __bf16* __restrict__ wf1, __bf16* __restrict__ wext1,
    __bf16* __restrict__ wf2, __bf16* __restrict__ wext2,
    int* __restrict__ counts, int nb)
{
    const int b = blockIdx.x, tid = threadIdx.x;
    if (b < 256) {
        const float* W = (b < 128) ? W1 : W2;
        __bf16* wf = (b < 128) ? wf1 : wf2;
        int idx = (b & 127) * 256 + tid;        // < 32768
        int j = idx & 7;
        int r = idx >> 3;
        int c = r & 15; r >>= 4;
        int t = r & 7;  r >>= 3;
        int kq = r & 15;
        int hl = r >> 4;
        float v = W[(t * 16 + c) * 128 + kq * 8 + j];
        __bf16 hi = (__bf16)v;
        wf[idx] = (hl == 0) ? hi : (__bf16)(v - (float)hi);
    } else if (b < 258) {
        const float* W  = (b == 256) ? W1 : W2;
        const float* al = (b == 256) ? al1 : al2;
        const float* ar = (b == 256) ? ar1 : ar2;
        __bf16* wext = (b == 256) ? wext1 : wext2;
        __shared__ float val[1024];
        #pragma unroll
        for (int ch = 0; ch < 4; ++ch) {
            int idx = ch * 256 + tid;           // < 1024
            int c = idx >> 7, k = idx & 127;
            int h = c & 3;
            const float* a = (c < 4) ? al : ar;
            float s = 0.f;
            for (int d = 0; d < 32; ++d)
                s += a[h * 32 + d] * W[(h * 32 + d) * 128 + k];
            val[c * 128 + k] = s;
        }
        __syncthreads();
        #pragma unroll
        for (int ch = 0; ch < 16; ++ch) {
            int idx = tid * 16 + ch;            // < 4096
            int j = idx & 7;
            int r = idx >> 3;
            int c = r & 15; r >>= 4;
            int kq = r & 15;
            int hl = r >> 4;
            float v = (c < 8) ? val[c * 128 + kq * 8 + j] : 0.f;
            __bf16 hi = (__bf16)v;
            wext[idx] = (hl == 0) ? hi : (__bf16)(v - (float)hi);
        }
    } else {
        int i0 = ((b - 258) * 256 + tid) * 4;
        if (i0 + 3 < nb) {
            *(int4*)&counts[i0] = make_int4(0, 0, 0, 0);
        } else {
            for (int i = i0; i < nb; ++i) counts[i] = 0;
        }
    }
}

// ---------------------------------------------------------------------------
// MFMA GEMM body (device fn): W-hi in LDS (32 KB), W-lo from global;
// processes tiles [tile0, tend) stride `stride`; X reg-prefetch.
// ---------------------------------------------------------------------------
template <typename XT>
__device__ __forceinline__ void gemm_body(
    const XT* __restrict__ X, const bf16x8* __restrict__ wf,
    const bf16x8* __restrict__ wext, _Float16* __restrict__ featH,
    float* __restrict__ el, float* __restrict__ er,
    int nnodes, int tile0, int tend, int stride, bf16x8* lw)
{
    const int tid = threadIdx.x;
    const int wave = tid >> 6, lane = tid & 63;
    const int l15 = lane & 15, quad = lane >> 4;

    int tile = tile0;
    float xr[32], xn[32];

    auto loadX = [&](int tl, float* dst) {
        int nodeA = tl * 64 + wave * 16 + l15;
        bool v = nodeA < nnodes;
        if constexpr (std::is_same<XT, float>::value) {
            const float4* xp = (const float4*)(X + (size_t)nodeA * 128);
            #pragma unroll
            for (int ks = 0; ks < 4; ++ks) {
                float4 a = v ? xp[ks * 8 + quad * 2]     : make_float4(0.f, 0.f, 0.f, 0.f);
                float4 b = v ? xp[ks * 8 + quad * 2 + 1] : make_float4(0.f, 0.f, 0.f, 0.f);
                dst[ks * 8 + 0] = a.x; dst[ks * 8 + 1] = a.y;
                dst[ks * 8 + 2] = a.z; dst[ks * 8 + 3] = a.w;
                dst[ks * 8 + 4] = b.x; dst[ks * 8 + 5] = b.y;
                dst[ks * 8 + 6] = b.z; dst[ks * 8 + 7] = b.w;
            }
        } else {
            const h16x8* xp = (const h16x8*)(X + (size_t)nodeA * 128);
            #pragma unroll
            for (int ks = 0; ks < 4; ++ks) {
                h16x8 hv;
                if (v) {
                    hv = xp[ks * 4 + quad];
                } else {
                    #pragma unroll
                    for (int j = 0; j < 8; ++j) hv[j] = (_Float16)0.f;
                }
                #pragma unroll
                for (int j = 0; j < 8; ++j) dst[ks * 8 + j] = (float)hv[j];
            }
        }
    };

    loadX(tile, xr);                      // issue X loads first
    for (int i = tid; i < 2048; i += 256) lw[i] = wf[i];
    __syncthreads();

    while (true) {
        int next = tile + stride;
        if (next < tend) loadX(next, xn);

        f32x4 acc[9];
        #pragma unroll
        for (int t = 0; t < 9; ++t) acc[t] = (f32x4){0.f, 0.f, 0.f, 0.f};

        #pragma unroll
        for (int ks = 0; ks < 4; ++ks) {
            bf16x8 ahi, alo;
            #pragma unroll
            for (int j = 0; j < 8; ++j) {
                float xv = xr[ks * 8 + j];
                __bf16 h = (__bf16)xv;
                ahi[j] = h;
                alo[j] = (__bf16)(xv - (float)h);
            }
            const int kq = ks * 4 + quad;

            {
                bf16x8 bh = wext[(kq) * 16 + l15];
                bf16x8 bl = wext[(16 + kq) * 16 + l15];
                acc[8] = __builtin_amdgcn_mfma_f32_16x16x32_bf16(ahi, bh, acc[8], 0, 0, 0);
                acc[8] = __builtin_amdgcn_mfma_f32_16x16x32_bf16(alo, bh, acc[8], 0, 0, 0);
                acc[8] = __builtin_amdgcn_mfma_f32_16x16x32_bf16(ahi, bl, acc[8], 0, 0, 0);
            }
            #pragma unroll
            for (int t = 0; t < 8; ++t) {
                bf16x8 bh = lw[(kq * 8 + t) * 16 + l15];
                bf16x8 bl = wf[2048 + (kq * 8 + t) * 16 + l15];   // lo from global
                acc[t] = __builtin_amdgcn_mfma_f32_16x16x32_bf16(ahi, bh, acc[t], 0, 0, 0);
                acc[t] = __builtin_amdgcn_mfma_f32_16x16x32_bf16(alo, bh, acc[t], 0, 0, 0);
                acc[t] = __builtin_amdgcn_mfma_f32_16x16x32_bf16(ahi, bl, acc[t], 0, 0, 0);
            }
        }

        const int nodeC = tile * 64 + wave * 16 + quad * 4;
        #pragma unroll
        for (int r = 0; r < 4; ++r) {
            int gn = nodeC + r;
            if (gn < nnodes) {
                #pragma unroll
                for (int t = 0; t < 8; ++t)
                    featH[(size_t)gn * 128 + t * 16 + l15] = (_Float16)acc[t][r];
            }
        }
        if (l15 < 8) {
            #pragma unroll
            for (int r = 0; r < 4; ++r) {
                int gn = nodeC + r;
                if (gn < nnodes) {
                    if (l15 < 4) el[gn * HEADS + l15] = acc[8][r];
                    else         er[gn * HEADS + (l15 - 4)] = acc[8][r];
                }
            }
        }

        if (next >= tend) break;
        #pragma unroll
        for (int i = 0; i < 32; ++i) xr[i] = xn[i];
        tile = next;
    }
}

// ---------------------------------------------------------------------------
// hist / scatter bodies (device fns), 8 edges/thread.
// bin = dst*8 + (src>>shift); hist captures within-bin rank from atomic return.
// ---------------------------------------------------------------------------
__device__ __forceinline__ void hist_body(
    const int* __restrict__ src, const int* __restrict__ dst,
    int* __restrict__ counts, int* __restrict__ rank, int nedges, int shift, int b)
{
    int i0 = (b * 256 + threadIdx.x) * 8;
    if (i0 + 7 < nedges) {
        int4 d0 = *(const int4*)&dst[i0];
        int4 d1 = *(const int4*)&dst[i0 + 4];
        int4 s0 = *(const int4*)&src[i0];
        int4 s1 = *(const int4*)&src[i0 + 4];
        int4 r0, r1;
        r0.x = atomicAdd(&counts[d0.x * NBUCK + (s0.x >> shift)], 1);
        r0.y = atomicAdd(&counts[d0.y * NBUCK + (s0.y >> shift)], 1);
        r0.z = atomicAdd(&counts[d0.z * NBUCK + (s0.z >> shift)], 1);
        r0.w = atomicAdd(&counts[d0.w * NBUCK + (s0.w >> shift)], 1);
        r1.x = atomicAdd(&counts[d1.x * NBUCK + (s1.x >> shift)], 1);
        r1.y = atomicAdd(&counts[d1.y * NBUCK + (s1.y >> shift)], 1);
        r1.z = atomicAdd(&counts[d1.z * NBUCK + (s1.z >> shift)], 1);
        r1.w = atomicAdd(&counts[d1.w * NBUCK + (s1.w >> shift)], 1);
        *(int4*)&rank[i0]     = r0;
        *(int4*)&rank[i0 + 4] = r1;
    } else {
        for (int i = i0; i < nedges; ++i)
            rank[i] = atomicAdd(&counts[dst[i] * NBUCK + (src[i] >> shift)], 1);
    }
}

__device__ __forceinline__ void scatter_body(
    const int* __restrict__ src, const int* __restrict__ dst,
    const int* __restrict__ rank, const int* __restrict__ offsets,
    int* __restrict__ csr_src, int nedges, int shift, int b)
{
    int i0 = (b * 256 + threadIdx.x) * 8;
    if (i0 + 7 < nedges) {
        int4 d0 = *(const int4*)&dst[i0];
        int4 d1 = *(const int4*)&dst[i0 + 4];
        int4 r0 = *(const int4*)&rank[i0];
        int4 r1 = *(const int4*)&rank[i0 + 4];
        int4 s0 = *(const int4*)&src[i0];
        int4 s1 = *(const int4*)&src[i0 + 4];
        csr_src[offsets[d0.x * NBUCK + (s0.x >> shift)] + r0.x] = s0.x;
        csr_src[offsets[d0.y * NBUCK + (s0.y >> shift)] + r0.y] = s0.y;
        csr_src[offsets[d0.z * NBUCK + (s0.z >> shift)] + r0.z] = s0.z;
        csr_src[offsets[d0.w * NBUCK + (s0.w >> shift)] + r0.w] = s0.w;
        csr_src[offsets[d1.x * NBUCK + (s1.x >> shift)] + r1.x] = s1.x;
        csr_src[offsets[d1.y * NBUCK + (s1.y >> shift)] + r1.y] = s1.y;
        csr_src[offsets[d1.z * NBUCK + (s1.z >> shift)] + r1.z] = s1.z;
        csr_src[offsets[d1.w * NBUCK + (s1.w >> shift)] + r1.w] = s1.w;
    } else {
        for (int i = i0; i < nedges; ++i)
            csr_src[offsets[dst[i] * NBUCK + (src[i] >> shift)] + rank[i]] = src[i];
    }
}

// ---------------------------------------------------------------------------
// Fused dispatches: layer-1 GEMM half ∥ hist, and GEMM half ∥ scatter.
// MFMA pipe (gemm blocks) and atomic/VMEM traffic (hist/scatter blocks)
// co-schedule on separate pipes (m114).
// ---------------------------------------------------------------------------
__global__ __launch_bounds__(256) void fused_gemm_hist(
    const float* __restrict__ X, const bf16x8* __restrict__ wf,
    const bf16x8* __restrict__ wext, _Float16* __restrict__ featH,
    float* __restrict__ el, float* __restrict__ er, int nnodes,
    int t0, int tend, int gemm_blocks,
    const int* __restrict__ src, const int* __restrict__ dst,
    int* __restrict__ counts, int* __restrict__ rank, int nedges, int shift)
{
    __shared__ bf16x8 lw[2048];
    if ((int)blockIdx.x < gemm_blocks)
        gemm_body<float>(X, wf, wext, featH, el, er, nnodes,
                         t0 + blockIdx.x, tend, gemm_blocks, lw);
    else
        hist_body(src, dst, counts, rank, nedges, shift, blockIdx.x - gemm_blocks);
}

__global__ __launch_bounds__(256) void fused_gemm_scatter(
    const float* __restrict__ X, const bf16x8* __restrict__ wf,
    const bf16x8* __restrict__ wext, _Float16* __restrict__ featH,
    float* __restrict__ el, float* __restrict__ er, int nnodes,
    int t0, int tend, int gemm_blocks,
    const int* __restrict__ src, const int* __restrict__ dst,
    const int* __restrict__ rank, const int* __restrict__ offsets,
    int* __restrict__ csr_src, int nedges, int shift)
{
    __shared__ bf16x8 lw[2048];
    if ((int)blockIdx.x < gemm_blocks)
        gemm_body<float>(X, wf, wext, featH, el, er, nnodes,
                         t0 + blockIdx.x, tend, gemm_blocks, lw);
    else
        scatter_body(src, dst, rank, offsets, csr_src, nedges, shift,
                     blockIdx.x - gemm_blocks);
}

// standalone GEMM (layer 2, fp16 input)
template <typename XT>
__global__ __launch_bounds__(256) void gemm_mfma_kernel(
    const XT* __restrict__ X, const bf16x8* __restrict__ wf,
    const bf16x8* __restrict__ wext, _Float16* __restrict__ featH,
    float* __restrict__ el, float* __restrict__ er, int nnodes, int ntiles)
{
    __shared__ bf16x8 lw[2048];
    gemm_body<XT>(X, wf, wext, featH, el, er, nnodes,
                  blockIdx.x, ntiles, gridDim.x, lw);
}

// ---------------------------------------------------------------------------
__global__ __launch_bounds__(256) void scan1_kernel(
    const int* __restrict__ counts, int* __restrict__ offsets,
    int* __restrict__ bsums, int n)
{
    __shared__ int wsums[4];
    const int tid = threadIdx.x, lane = tid & 63, w = tid >> 6;
    const int i = blockIdx.x * 1024 + tid * 4;

    int4 v = make_int4(0, 0, 0, 0);
    if (i + 3 < n) v = *(const int4*)&counts[i];
    else {
        if (i < n)     v.x = counts[i];
        if (i + 1 < n) v.y = counts[i + 1];
        if (i + 2 < n) v.z = counts[i + 2];
    }
    int s0 = v.x, s1 = s0 + v.y, s2 = s1 + v.z, s3 = s2 + v.w;

    int x = s3;
    #pragma unroll
    for (int off = 1; off < 64; off <<= 1) {
        int t = __shfl_up(x, off, 64);
        if (lane >= off) x += t;
    }
    if (lane == 63) wsums[w] = x;
    __syncthreads();
    int wbase = 0;
    #pragma unroll
    for (int k = 0; k < 4; ++k) if (k < w) wbase += wsums[k];

    int tbase = wbase + x - s3;
    if (i < n)     offsets[i]     = tbase;
    if (i + 1 < n) offsets[i + 1] = tbase + s0;
    if (i + 2 < n) offsets[i + 2] = tbase + s1;
    if (i + 3 < n) offsets[i + 3] = tbase + s2;
    if (tid == 255) bsums[blockIdx.x] = wbase + x;
}

__global__ __launch_bounds__(256) void scan23_kernel(
    int* __restrict__ offsets, const int* __restrict__ bsums, int n, int nedges)
{
    __shared__ int sbase;
    const int tid = threadIdx.x, b = blockIdx.x;
    if (tid < 64) {
        int s = 0;
        for (int i = tid; i < b; i += 64) s += bsums[i];
        #pragma unroll
        for (int off = 1; off < 64; off <<= 1) s += __shfl_xor(s, off, 64);
        if (tid == 0) sbase = s;
    }
    __syncthreads();
    const int base = sbase;
    const int i = b * 1024 + tid * 4;
    #pragma unroll
    for (int k = 0; k < 4; ++k)
        if (i + k < n) offsets[i + k] += base;
    if (b == 0 && tid == 0) offsets[n] = nedges;
}

// ---------------------------------------------------------------------------
// Gather aggregation: one wave per node, 4 edges/iter, depth-2 pipeline.
// ---------------------------------------------------------------------------
template <bool MEAN>
__global__ __launch_bounds__(256) void aggregate_kernel(
    const _Float16* __restrict__ featH, const float* __restrict__ el,
    const float* __restrict__ er, const int* __restrict__ offsets,
    const int* __restrict__ csr_src, void* __restrict__ outp, int nnodes)
{
    const int n = (blockIdx.x * 256 + threadIdx.x) >> 6;   // wave-uniform
    if (n >= nnodes) return;
    const int lane = threadIdx.x & 63;
    const int g = lane >> 4, u = lane & 15, h = u >> 2;
    const int beg = offsets[n * NBUCK], end = offsets[n * NBUCK + NBUCK];
    const float ern = er[n * HEADS + h];
    const int iters = (end - beg + 3) >> 2;

    float a[8];
    #pragma unroll
    for (int p = 0; p < 8; ++p) a[p] = 0.f;
    float sw = 0.f;

    const h16x8* __restrict__ frow = (const h16x8*)featH;

    int ja = beg + g;
    int jb = ja + 4;
    bool va = ja < end, vb = jb < end;
    int sa = va ? csr_src[ja] : 0;
    int sb = vb ? csr_src[jb] : 0;
    float qa = el[sa * HEADS + h];
    float qb = el[sb * HEADS + h];
    h16x8 fa = frow[(size_t)sa * 16 + u];
    h16x8 fb = frow[(size_t)sb * 16 + u];

    for (int it = 0; it < iters; ++it) {
        int jc = ja + 8;
        bool vc = jc < end;
        int sc = vc ? csr_src[jc] : 0;
        float qc = el[sc * HEADS + h];
        h16x8 fc = frow[(size_t)sc * 16 + u];

        float e = qa + ern;
        e = e > 0.f ? e : NEG * e;
        float w = va ? __expf(e) : 0.f;
        #pragma unroll
        for (int p = 0; p < 8; ++p) a[p] += w * (float)fa[p];
        sw += w;

        ja = jb; va = vb; sa = sb; qa = qb; fa = fb;
        jb = jc; vb = vc; sb = sc; qb = qc; fb = fc;
    }

    #pragma unroll
    for (int p = 0; p < 8; ++p) {
        a[p] += __shfl_xor(a[p], 16, 64);
        a[p] += __shfl_xor(a[p], 32, 64);
    }
    sw += __shfl_xor(sw, 16, 64);
    sw += __shfl_xor(sw, 32, 64);

    float inv = sw > 0.f ? 1.f / sw : 0.f;
    float r[8];
    #pragma unroll
    for (int p = 0; p < 8; ++p) {
        float t = a[p] * inv;
        r[p] = t > 0.f ? t : expm1f(t);
    }

    if (!MEAN) {
        if (g == 0) {
            h16x8 o;
            #pragma unroll
            for (int p = 0; p < 8; ++p) o[p] = (_Float16)r[p];
            ((h16x8*)outp)[(size_t)n * 16 + u] = o;
        }
    } else {
        #pragma unroll
        for (int p = 0; p < 8; ++p) {
            r[p] += __shfl_xor(r[p], 4, 64);
            r[p] += __shfl_xor(r[p], 8, 64);
        }
        if (g == 0 && u < 4) {
            float* out = (float*)outp;
            float4* o4 = (float4*)(out + (size_t)n * 32 + u * 8);
            o4[0] = make_float4(0.25f * r[0], 0.25f * r[1], 0.25f * r[2], 0.25f * r[3]);
            o4[1] = make_float4(0.25f * r[4], 0.25f * r[5], 0.25f * r[6], 0.25f * r[7]);
        }
    }
}

// ---------------------------------------------------------------------------
extern "C" void kernel_launch(void* const* d_in, const int* in_sizes, int n_in,
                              void* d_out, int out_size, void* d_ws, size_t ws_size,
                              hipStream_t stream)
{
    const float* x   = (const float*)d_in[0];
    const int*   src = (const int*)d_in[1];
    const int*   dst = (const int*)d_in[2];
    const float* W1  = (const float*)d_in[3];
    const float* al1 = (const float*)d_in[4];
    const float* ar1 = (const float*)d_in[5];
    const float* W2  = (const float*)d_in[6];
    const float* al2 = (const float*)d_in[7];
    const float* ar2 = (const float*)d_in[8];

    const int N = in_sizes[0] / FDIM;
    const int E = in_sizes[1];
    const int NB = N * NBUCK;

    int shift = 0;
    while (((N - 1) >> shift) > (NBUCK - 1)) ++shift;

    _Float16* h1 = (_Float16*)d_ws;
    _Float16* featH = h1 + (size_t)N * FDIM;
    float* el = (float*)(featH + (size_t)N * FDIM);
    float* er = el + (size_t)N * HEADS;
    int* counts  = (int*)(er + (size_t)N * HEADS);
    int* offsets = counts + NB;
    int* rank    = offsets + (NB + 1);
    int* csr_src = rank + E;
    int* bsums   = csr_src + E;
    uintptr_t wp = ((uintptr_t)(bsums + 512) + 63) & ~(uintptr_t)63;
    __bf16* wf1   = (__bf16*)wp;             // 32768 bf16
    __bf16* wext1 = wf1 + 32768;             // 4096 bf16
    __bf16* wf2   = wext1 + 4096;
    __bf16* wext2 = wf2 + 32768;

    const int ntiles = (N + 63) / 64;
    const int halfT  = (ntiles + 1) / 2;
    const int gA = halfT < 256 ? halfT : 256;
    const int gB = (ntiles - halfT) < 256 ? (ntiles - halfT) : 256;
    const int edge8_grid = ((E + 7) / 8 + 255) / 256;
    const int agg_grid  = (N + 3) / 4;             // 1 wave/node, 4 waves/block
    const int nscan     = (NB + 1023) / 1024;
    const int zblocks   = ((NB + 3) / 4 + 255) / 256;
    const int g2 = ntiles < 512 ? ntiles : 512;

    // ---- W preprocessing + counts zeroing ----
    prep_kernel<<<258 + zblocks, 256, 0, stream>>>(
        W1, al1, ar1, W2, al2, ar2, wf1, wext1, wf2, wext2, counts, NB);

    // ---- [gemm1 first half ∥ hist] ----
    fused_gemm_hist<<<gA + edge8_grid, 256, 0, stream>>>(
        x, (const bf16x8*)wf1, (const bf16x8*)wext1, featH, el, er, N,
        0, halfT, gA, src, dst, counts, rank, E, shift);

    scan1_kernel<<<nscan, 256, 0, stream>>>(counts, offsets, bsums, NB);
    scan23_kernel<<<nscan, 256, 0, stream>>>(offsets, bsums, NB, E);

    // ---- [gemm1 second half ∥ scatter] ----
    fused_gemm_scatter<<<gB + edge8_grid, 256, 0, stream>>>(
        x, (const bf16x8*)wf1, (const bf16x8*)wext1, featH, el, er, N,
        halfT, ntiles, gB, src, dst, rank, offsets, csr_src, E, shift);

    // ---- layer 1 aggregate ----
    aggregate_kernel<false><<<agg_grid, 256, 0, stream>>>(
        featH, el, er, offsets, csr_src, (void*)h1, N);

    // ---- layer 2 ----
    gemm_mfma_kernel<_Float16><<<g2, 256, 0, stream>>>(
        h1, (const bf16x8*)wf2, (const bf16x8*)wext2, featH, el, er, N, ntiles);
    aggregate_kernel<true><<<agg_grid, 256, 0, stream>>>(
        featH, el, er, offsets, csr_src, d_out, N);
}